// Round 4
// baseline (537.573 us; speedup 1.0000x reference)
//
#include <hip/hip_runtime.h>

// Problem constants: B=4, S=1024, D=1024, H=16, HD=64
constexpr int Bc = 4, Sc = 1024, Dc = 1024, Hc = 16, HDc = 64;
constexpr long BSD = (long)Bc * Sc * Dc;      // 4,194,304
constexpr long MM  = (long)Dc * Dc;           // 1,048,576

typedef __attribute__((ext_vector_type(8))) short bf16x8;   // 8 bf16 = 4 VGPRs
typedef __attribute__((ext_vector_type(4))) short bf16x4;   // 4 bf16 = 2 VGPRs
typedef __attribute__((ext_vector_type(4))) float f32x4;
typedef unsigned int u32;

__device__ inline ushort f2bf(float f) {  // round-to-nearest-even
    union { float f; unsigned i; } v; v.f = f;
    unsigned lsb = (v.i >> 16) & 1;
    v.i += 0x7fffu + lsb;
    return (ushort)(v.i >> 16);
}

// ---------------------------------------------------------------------------
// One-launch fp32 -> bf16 convert of q,k,v,Wq,Wk,Wv,Wo into ws.
// ---------------------------------------------------------------------------
__global__ __launch_bounds__(256)
void cvt_all(const float* __restrict__ q, const float* __restrict__ k,
             const float* __restrict__ v, const float* __restrict__ Wq,
             const float* __restrict__ Wk, const float* __restrict__ Wv,
             const float* __restrict__ Wo, ushort* __restrict__ dst)
{
    const int t = blockIdx.y;
    const long n = (t < 3) ? BSD : MM;
    const long i = ((long)blockIdx.x * 256 + threadIdx.x) * 8;
    if (i >= n) return;
    const float* src; long off;
    switch (t) {
        case 0: src = q;  off = 0;            break;
        case 1: src = k;  off = BSD;          break;
        case 2: src = v;  off = 2 * BSD;      break;
        case 3: src = Wq; off = 3 * BSD;      break;
        case 4: src = Wk; off = 3 * BSD + MM; break;
        case 5: src = Wv; off = 3 * BSD + 2 * MM; break;
        default: src = Wo; off = 3 * BSD + 3 * MM; break;
    }
    f32x4 a = *(const f32x4*)(src + i);
    f32x4 b = *(const f32x4*)(src + i + 4);
    bf16x8 r;
    #pragma unroll
    for (int j = 0; j < 4; j++) { r[j] = (short)f2bf(a[j]); r[j + 4] = (short)f2bf(b[j]); }
    *(bf16x8*)(dst + off + i) = r;
}

// ---------------------------------------------------------------------------
// Stage one 128x32 bf16 tile into LDS via global_load_lds (width 16).
// ---------------------------------------------------------------------------
__device__ inline void stage_tile(const ushort* __restrict__ G, int ld, int rowbase,
                                  int kt, ushort* lds, int wave, int lane)
{
    #pragma unroll
    for (int j = 0; j < 2; j++) {
        const int c = wave * 128 + j * 64 + lane;
        const int row = c >> 2, k8 = c & 3;
        const ushort* g = G + (long)(rowbase + row) * ld + kt + k8 * 8;
        ushort* l = lds + (wave * 128 + j * 64) * 8;   // wave-uniform base
        __builtin_amdgcn_global_load_lds(
            (const __attribute__((address_space(1))) u32*)(const void*)g,
            (__attribute__((address_space(3))) u32*)(void*)l, 16, 0, 0);
    }
}

// ---------------------------------------------------------------------------
// Shared m97-style main loop: acc[4][4] += A[128xK] * Bt[128xK]^T tile-product.
// 128x128 block tile, BK=32, 256 threads, double-buffered LDS, one barrier/iter.
// ---------------------------------------------------------------------------
__device__ inline void gemm_core(const ushort* __restrict__ A, int lda,
                                 const ushort* __restrict__ Bt, int ldb, int K,
                                 int mtile, int ntile,
                                 ushort (*As)[128 * 32], ushort (*Bs)[128 * 32],
                                 f32x4 (*acc)[4], int wave, int lane)
{
    const int l15 = lane & 15, quad = lane >> 4;
    const int wr = wave >> 1, wc = wave & 1;

    stage_tile(A,  lda, mtile, 0, As[0], wave, lane);
    stage_tile(Bt, ldb, ntile, 0, Bs[0], wave, lane);
    __syncthreads();

    int buf = 0;
    for (int kt = 0; kt < K; kt += 32) {
        if (kt + 32 < K) {
            stage_tile(A,  lda, mtile, kt + 32, As[buf ^ 1], wave, lane);
            stage_tile(Bt, ldb, ntile, kt + 32, Bs[buf ^ 1], wave, lane);
        }
        bf16x8 af[4], bfr[4];
        #pragma unroll
        for (int mt = 0; mt < 4; mt++)
            af[mt] = *(const bf16x8*)(As[buf] + (wr * 64 + mt * 16 + l15) * 32 + quad * 8);
        #pragma unroll
        for (int nt = 0; nt < 4; nt++)
            bfr[nt] = *(const bf16x8*)(Bs[buf] + (wc * 64 + nt * 16 + l15) * 32 + quad * 8);
        #pragma unroll
        for (int mt = 0; mt < 4; mt++)
            #pragma unroll
            for (int nt = 0; nt < 4; nt++)
                acc[mt][nt] = __builtin_amdgcn_mfma_f32_16x16x32_bf16(af[mt], bfr[nt], acc[mt][nt], 0, 0, 0);
        __syncthreads();   // drains prefetch vmcnt + protects LDS reuse
        buf ^= 1;
    }
}

// ---------------------------------------------------------------------------
// Batched Q/K/V projection: grid.z = 0,1,2 selects (input, weight, bias, dest).
// z<2: bf16 out at QK + z*BSD (row-major). z==2: Vt[b,h,d,s] scatter.
// ---------------------------------------------------------------------------
__global__ __launch_bounds__(256)
void gemm_qkv(const ushort* __restrict__ ws, const float* __restrict__ bq,
              const float* __restrict__ bk, const float* __restrict__ bv,
              ushort* __restrict__ QK, ushort* __restrict__ Vt)
{
    __shared__ ushort As[2][128 * 32];
    __shared__ ushort Bs[2][128 * 32];

    const int z = blockIdx.z;
    const ushort* A  = ws + (long)z * BSD;
    const ushort* Bt = ws + 3 * BSD + (long)z * MM;
    const float* bias = (z == 0) ? bq : (z == 1) ? bk : bv;

    const int lane = threadIdx.x & 63, wave = threadIdx.x >> 6;
    const int l15 = lane & 15, quad = lane >> 4;
    const int wr = wave >> 1, wc = wave & 1;
    const int mtile = blockIdx.y * 128, ntile = blockIdx.x * 128;

    f32x4 acc[4][4] = {};
    gemm_core(A, Dc, Bt, Dc, Dc, mtile, ntile, As, Bs, acc, wave, lane);

    #pragma unroll
    for (int mt = 0; mt < 4; mt++) {
        #pragma unroll
        for (int nt = 0; nt < 4; nt++) {
            const int col = ntile + wc * 64 + nt * 16 + l15;
            const float bb = bias[col];
            #pragma unroll
            for (int i = 0; i < 4; i++) {
                const int r = mtile + wr * 64 + mt * 16 + quad * 4 + i;
                const float vv = acc[mt][nt][i] + bb;
                if (z < 2) {
                    QK[(long)z * BSD + (long)r * Dc + col] = f2bf(vv);
                } else {
                    const int b = r >> 10, sI = r & 1023;
                    const int hh = col >> 6, dd = col & 63;
                    Vt[(long)((b * Hc + hh) * HDc + dd) * Sc + sI] = f2bf(vv);
                }
            }
        }
    }
}

// ---------------------------------------------------------------------------
// Output projection: out = Ctx @ Wo^T + bo, fp32 out.
// ---------------------------------------------------------------------------
__global__ __launch_bounds__(256)
void gemm_out(const ushort* __restrict__ A, const ushort* __restrict__ Bt,
              const float* __restrict__ bias, float* __restrict__ C)
{
    __shared__ ushort As[2][128 * 32];
    __shared__ ushort Bs[2][128 * 32];

    const int lane = threadIdx.x & 63, wave = threadIdx.x >> 6;
    const int l15 = lane & 15, quad = lane >> 4;
    const int wr = wave >> 1, wc = wave & 1;
    const int mtile = blockIdx.y * 128, ntile = blockIdx.x * 128;

    f32x4 acc[4][4] = {};
    gemm_core(A, Dc, Bt, Dc, Dc, mtile, ntile, As, Bs, acc, wave, lane);

    #pragma unroll
    for (int mt = 0; mt < 4; mt++) {
        #pragma unroll
        for (int nt = 0; nt < 4; nt++) {
            const int col = ntile + wc * 64 + nt * 16 + l15;
            const float bb = bias[col];
            #pragma unroll
            for (int i = 0; i < 4; i++) {
                const int r = mtile + wr * 64 + mt * 16 + quad * 4 + i;
                C[(long)r * Dc + col] = acc[mt][nt][i] + bb;
            }
        }
    }
}

// ---------------------------------------------------------------------------
// Fused scores + mask + softmax + PV.
// Grid: (S/16, B*H), 256 threads (4 waves). Block owns 16 q-rows, all 1024 k.
//  Phase 1: S = Q K^T into LDS fp32 (16B-chunk XOR swizzle: chunk ^= row&7).
//  Phase 2: row softmax (vectorized: lane owns cols jj*256+lane*4+e).
//           Writes fp32 attn (float4 stores) AND bf16 P in-place into the
//           first 2KB of each score row (8B-unit swizzle: unit ^= (row&7)<<1).
//  Phase 3: ctx = P @ V; A-frag is ONE swizzled ds_read_b128 (no f2bf VALU).
// LDS is a union so the fp32->bf16 in-place repack is alias/order-safe:
// each wave owns its 4 rows exclusively; all reads of a row precede writes;
// per-wave DS ops execute in order; rows are disjoint 4KB regions.
// ---------------------------------------------------------------------------
__device__ inline int sc_idx(int row, int col) {
    return row * 1024 + ((((col >> 2) ^ (row & 7)) << 2) | (col & 3));
}

__global__ __launch_bounds__(256)
void attn_fused(const ushort* __restrict__ Q, const ushort* __restrict__ Kp,
                const ushort* __restrict__ Vt, const int* __restrict__ mask,
                float* __restrict__ attn, ushort* __restrict__ Ctx)
{
    __shared__ union { float f[16 * 1024]; ushort u[16 * 2048]; } sc;  // 64 KB

    const int bh = blockIdx.y;
    const int b = bh >> 4, h = bh & 15;
    const int qbase = blockIdx.x * 16;
    const int lane = threadIdx.x & 63;
    const int wave = threadIdx.x >> 6;
    const int l15 = lane & 15, quad = lane >> 4;

    const ushort* Qh = Q  + (long)b * Sc * Dc + h * HDc;
    const ushort* Kh = Kp + (long)b * Sc * Dc + h * HDc;

    const ushort* qrow = Qh + (long)(qbase + l15) * Dc + quad * 8;
    const bf16x8 a0 = *(const bf16x8*)(qrow);
    const bf16x8 a1 = *(const bf16x8*)(qrow + 32);

    // mask bits for this lane's 16 columns: col = jj*256 + lane*4 + e
    unsigned mbits = 0;
    {
        const int4* mp = (const int4*)(mask + b * Sc);
        #pragma unroll
        for (int jj = 0; jj < 4; jj++) {
            const int4 mm = mp[jj * 64 + lane];
            if (mm.x == 0) mbits |= 1u << (jj * 4 + 0);
            if (mm.y == 0) mbits |= 1u << (jj * 4 + 1);
            if (mm.z == 0) mbits |= 1u << (jj * 4 + 2);
            if (mm.w == 0) mbits |= 1u << (jj * 4 + 3);
        }
    }

    // Phase 1: scores. Wave w covers k-columns [w*256, w*256+256).
    // unroll 4: keeps ~8 K-row loads in flight ahead of the MFMA chain.
    #pragma unroll 4
    for (int t = 0; t < 16; t++) {
        const int ct = wave * 16 + t;
        const ushort* krow = Kh + (long)(ct * 16 + l15) * Dc + quad * 8;
        const bf16x8 b0 = *(const bf16x8*)(krow);
        const bf16x8 b1 = *(const bf16x8*)(krow + 32);
        f32x4 acc = {};
        __builtin_amdgcn_s_setprio(1);
        acc = __builtin_amdgcn_mfma_f32_16x16x32_bf16(a0, b0, acc, 0, 0, 0);
        acc = __builtin_amdgcn_mfma_f32_16x16x32_bf16(a1, b1, acc, 0, 0, 0);
        __builtin_amdgcn_s_setprio(0);
        const int col = ct * 16 + l15;
        #pragma unroll
        for (int i = 0; i < 4; i++) sc.f[sc_idx(quad * 4 + i, col)] = acc[i];
    }
    __syncthreads();

    // Phase 2: softmax over each wave's 4 rows (r = wave*4+rr).
    #pragma unroll 1
    for (int rr = 0; rr < 4; rr++) {
        const int r = wave * 4 + rr;
        const int sw = r & 7;
        float v[16];
        float mx = -3.0e38f;
        #pragma unroll
        for (int jj = 0; jj < 4; jj++) {
            const int c = jj * 64 + lane;                       // logical f32 16B-chunk
            const f32x4 x = *(const f32x4*)(sc.f + r * 1024 + ((c ^ sw) << 2));
            #pragma unroll
            for (int e = 0; e < 4; e++) {
                float s = x[e] * 0.125f;                        // 1/sqrt(64)
                if (mbits & (1u << (jj * 4 + e))) s = -1e10f;
                v[jj * 4 + e] = s;
                mx = fmaxf(mx, s);
            }
        }
        #pragma unroll
        for (int off = 32; off >= 1; off >>= 1) mx = fmaxf(mx, __shfl_xor(mx, off, 64));
        float sum = 0.0f;
        #pragma unroll
        for (int i = 0; i < 16; i++) { v[i] = __expf(v[i] - mx); sum += v[i]; }
        #pragma unroll
        for (int off = 32; off >= 1; off >>= 1) sum += __shfl_xor(sum, off, 64);
        const float inv = 1.0f / sum;
        #pragma unroll
        for (int i = 0; i < 16; i++) v[i] *= inv;

        // fp32 attn output (mandatory): float4 per jj, fully coalesced.
        float* arow = attn + ((long)bh * Sc + qbase + r) * Sc + lane * 4;
        #pragma unroll
        for (int jj = 0; jj < 4; jj++) {
            f32x4 o;
            #pragma unroll
            for (int e = 0; e < 4; e++) o[e] = v[jj * 4 + e];
            *(f32x4*)(arow + jj * 256) = o;
        }

        // bf16 P in-place into row r's first 2KB. 8B-unit swizzle: u ^= (r&7)<<1.
        ushort* prow = sc.u + r * 2048;
        const int sw2 = sw << 1;
        #pragma unroll
        for (int jj = 0; jj < 4; jj++) {
            const int u8 = jj * 64 + lane;                      // logical 8B unit (4 bf16)
            bf16x4 pk;
            #pragma unroll
            for (int e = 0; e < 4; e++) pk[e] = (short)f2bf(v[jj * 4 + e]);
            *(bf16x4*)(prow + ((u8 ^ sw2) << 2)) = pk;
        }
    }
    __syncthreads();

    // Phase 3: ctx = P @ V. Wave w owns d-tile [w*16, w*16+16); 4 indep k-chains.
    // A-frag: one ds_read_b128 of bf16 P (row l15), swizzle-consistent with phase 2.
    f32x4 pacc[4] = {};
    const ushort* prow = sc.u + l15 * 2048;
    const int sw2 = (l15 & 7) << 1;
    const ushort* Vh = Vt + (long)bh * HDc * Sc + (long)(wave * 16 + l15) * Sc + quad * 8;
    for (int k0 = 0; k0 < Sc; k0 += 128) {
        bf16x8 af[4], bv4[4];
        #pragma unroll
        for (int u = 0; u < 4; u++) {
            const int k = k0 + u * 32 + quad * 8;               // k>>2 is even
            af[u]  = *(const bf16x8*)(prow + (((k >> 2) ^ sw2) << 2));
            bv4[u] = *(const bf16x8*)(Vh + k0 + u * 32);
        }
        __builtin_amdgcn_s_setprio(1);
        #pragma unroll
        for (int u = 0; u < 4; u++)
            pacc[u] = __builtin_amdgcn_mfma_f32_16x16x32_bf16(af[u], bv4[u], pacc[u], 0, 0, 0);
        __builtin_amdgcn_s_setprio(0);
    }
    f32x4 acc;
    #pragma unroll
    for (int i = 0; i < 4; i++) acc[i] = (pacc[0][i] + pacc[1][i]) + (pacc[2][i] + pacc[3][i]);

    const int dcol = h * HDc + wave * 16 + l15;
    #pragma unroll
    for (int i = 0; i < 4; i++) {
        const int r = qbase + quad * 4 + i;
        Ctx[(long)b * Sc * Dc + (long)r * Dc + dcol] = f2bf(acc[i]);
    }
}

// ---------------------------------------------------------------------------
extern "C" void kernel_launch(void* const* d_in, const int* in_sizes, int n_in,
                              void* d_out, int out_size, void* d_ws, size_t ws_size,
                              hipStream_t stream)
{
    const float* q    = (const float*)d_in[0];
    const float* k    = (const float*)d_in[1];
    const float* v    = (const float*)d_in[2];
    const int*   mask = (const int*)  d_in[3];
    const float* Wq   = (const float*)d_in[4];
    const float* bq   = (const float*)d_in[5];
    const float* Wk   = (const float*)d_in[6];
    const float* bk   = (const float*)d_in[7];
    const float* Wv   = (const float*)d_in[8];
    const float* bv   = (const float*)d_in[9];
    const float* Wo   = (const float*)d_in[10];
    const float* bo   = (const float*)d_in[11];

    ushort* ws  = (ushort*)d_ws;
    ushort* Wob = ws + 3 * BSD + 3 * MM;
    ushort* Qp  = ws + 3 * BSD + 4 * MM;     // projected Q bf16
    ushort* Kpp = Qp + BSD;                  // projected K bf16
    ushort* Vt  = Kpp + BSD;                 // Vt[b,h,d,s] bf16
    ushort* Ctx = Vt + BSD;                  // ctx bf16, (B,S,D) layout

    float* out  = (float*)d_out;             // output 0: (B,S,D) fp32
    float* attn = out + BSD;                 // output 1: (B,H,S,S) fp32

    const dim3 blk(256);

    // fp32 -> bf16 converts (one launch, 7 tensors)
    cvt_all<<<dim3(BSD / (256 * 8), 7), blk, 0, stream>>>(q, k, v, Wq, Wk, Wv, Wo, ws);

    // Q,K,V projections batched: grid (8,32,3) = 768 blocks (~3 blocks/CU).
    gemm_qkv<<<dim3(8, 32, 3), blk, 0, stream>>>(ws, bq, bk, bv, Qp, Vt);

    // Fused scores + softmax + PV: writes attn (fp32 output) and Ctx (bf16).
    attn_fused<<<dim3(Sc / 16, Bc * Hc), blk, 0, stream>>>(Qp, Kpp, Vt, mask, attn, Ctx);

    // out = ctx @ Wo^T + bo (fp32 out).
    gemm_out<<<dim3(8, 32), blk, 0, stream>>>(Ctx, Wob, bo, out);
}